// Round 2
// 347.749 us; speedup vs baseline: 1.1192x; 1.1192x over previous
//
#include <hip/hip_runtime.h>

#define RES   128
#define FEAT  1024   // map_num(128) * feat_dim(8)
#define NBINS (RES * RES)

typedef float nfloat4 __attribute__((ext_vector_type(4)));   // native vec for NT store

// ---------------------------------------------------------------------------
// Pass B: histogram points per grid cell
__global__ __launch_bounds__(256)
void hist_kernel(const float* __restrict__ inputs, unsigned* __restrict__ hist, int N)
{
    int p = blockIdx.x * 256 + threadIdx.x;
    if (p >= N) return;
    const float2 uv = ((const float2*)inputs)[p];
    int i0 = (int)floorf(uv.x * (float)(RES - 1));
    int i1 = (int)floorf(uv.y * (float)(RES - 1));
    atomicAdd(&hist[i0 * RES + i1], 1u);
}

// ---------------------------------------------------------------------------
// Pass C: in-place exclusive scan of 16384 bins (single block, 256 thr x 64)
__global__ __launch_bounds__(256)
void scan_kernel(unsigned* __restrict__ hist)
{
    __shared__ unsigned part[256];
    int t = threadIdx.x;
    int base = t * 64;
    unsigned s = 0;
    for (int k = 0; k < 64; ++k) s += hist[base + k];
    part[t] = s;
    __syncthreads();
    if (t == 0) {
        unsigned run = 0;
        for (int i = 0; i < 256; ++i) { unsigned v = part[i]; part[i] = run; run += v; }
    }
    __syncthreads();
    unsigned run = part[t];
    for (int k = 0; k < 64; ++k) { unsigned v = hist[base + k]; hist[base + k] = run; run += v; }
}

// ---------------------------------------------------------------------------
// Pass D: scatter point indices into cell-sorted order.
// After this pass hist[c] == inclusive end offset of cell c.
__global__ __launch_bounds__(256)
void scatter_kernel(const float* __restrict__ inputs, unsigned* __restrict__ hist,
                    unsigned* __restrict__ order, int N)
{
    int p = blockIdx.x * 256 + threadIdx.x;
    if (p >= N) return;
    const float2 uv = ((const float2*)inputs)[p];
    int i0 = (int)floorf(uv.x * (float)(RES - 1));
    int i1 = (int)floorf(uv.y * (float)(RES - 1));
    unsigned pos = atomicAdd(&hist[i0 * RES + i1], 1u);
    order[pos] = (unsigned)p;
}

// ---------------------------------------------------------------------------
// Pass E: one block per CELL. Load the cell's 4 neighbor rows into registers
// once, stage the cell's point list (index + uv) through LDS in one parallel
// step, then the inner loop is pure VALU + one NT wave-store per point.
// XCD-aware swizzle: block b -> XCD (b%8) gets a contiguous cell range
// (good L2 locality for the row panel that XCD touches).
__global__ __launch_bounds__(256)
void DenseMap_cell_kernel(const float* __restrict__ inputs,
                          const float* __restrict__ emb,
                          const unsigned* __restrict__ hist,   // inclusive ends
                          const unsigned* __restrict__ order,
                          float* __restrict__ out,
                          int chunk)
{
    const int b    = blockIdx.x;
    const int cell = (chunk > 0) ? ((b & 7) * chunk + (b >> 3)) : b;
    const int c    = threadIdx.x;

    const unsigned start = (cell == 0) ? 0u : hist[cell - 1];
    const unsigned end   = hist[cell];
    if (start == end) return;             // boundary cells (i0==127 || i1==127)
                                          // are always empty -> no OOB rows below

    const int i0 = cell >> 7;             // cell = i0*RES + i1
    const int i1 = cell & (RES - 1);

    const long base = (long)cell * FEAT;
    const float4 r00 = ((const float4*)(emb + base))[c];
    const float4 r01 = ((const float4*)(emb + base + FEAT))[c];
    const float4 r10 = ((const float4*)(emb + base + (long)RES * FEAT))[c];
    const float4 r11 = ((const float4*)(emb + base + (long)RES * FEAT + FEAT))[c];

    __shared__ unsigned sp[256];
    __shared__ float    sx0[256];
    __shared__ float    sx1[256];

    for (unsigned cb = start; cb < end; cb += 256u) {
        const int cnt = (int)min(end - cb, 256u);
        if (c < cnt) {
            const unsigned p  = order[cb + c];
            const float2   uv = ((const float2*)inputs)[p];
            sp[c]  = p;
            sx0[c] = uv.x;
            sx1[c] = uv.y;
        }
        __syncthreads();

        for (int j = 0; j < cnt; ++j) {
            const float x0  = sx0[j] * (float)(RES - 1);
            const float x1  = sx1[j] * (float)(RES - 1);
            const float xf0 = x0 - (float)i0;   // == x0 - floorf(x0) for points in this cell
            const float xf1 = x1 - (float)i1;

            const float w00 = (1.0f - xf0) * (1.0f - xf1);
            const float w01 = (1.0f - xf0) * xf1;
            const float w10 = xf0 * (1.0f - xf1);
            const float w11 = xf0 * xf1;

            nfloat4 r;
            r.x = r00.x * w00 + r01.x * w01 + r10.x * w10 + r11.x * w11;
            r.y = r00.y * w00 + r01.y * w01 + r10.y * w10 + r11.y * w11;
            r.z = r00.z * w00 + r01.z * w01 + r10.z * w10 + r11.z * w11;
            r.w = r00.w * w00 + r01.w * w01 + r10.w * w10 + r11.w * w11;

            __builtin_nontemporal_store(r, ((nfloat4*)(out + (long)sp[j] * FEAT)) + c);
        }
        __syncthreads();
    }
}

// ---------------------------------------------------------------------------
// Fallback: used only if ws is too small for the sort buffers.
__global__ __launch_bounds__(256)
void DenseMap_fallback_kernel(const float* __restrict__ inputs,
                              const float* __restrict__ emb,
                              float* __restrict__ out)
{
    const int p = blockIdx.x;
    const int c = threadIdx.x;

    const float x0 = inputs[2 * p + 0] * (float)(RES - 1);
    const float x1 = inputs[2 * p + 1] * (float)(RES - 1);
    const float f0 = floorf(x0);
    const float f1 = floorf(x1);
    const int   i0 = (int)f0;
    const int   i1 = (int)f1;
    const float xf0 = x0 - f0;
    const float xf1 = x1 - f1;

    const float w00 = (1.0f - xf0) * (1.0f - xf1);
    const float w01 = (1.0f - xf0) * xf1;
    const float w10 = xf0 * (1.0f - xf1);
    const float w11 = xf0 * xf1;

    const long base = (long)(i0 * RES + i1) * FEAT;
    const float4 a = ((const float4*)(emb + base))[c];
    const float4 b = ((const float4*)(emb + base + FEAT))[c];
    const float4 g = ((const float4*)(emb + base + (long)RES * FEAT))[c];
    const float4 h = ((const float4*)(emb + base + (long)RES * FEAT + FEAT))[c];

    float4 r;
    r.x = a.x * w00 + b.x * w01 + g.x * w10 + h.x * w11;
    r.y = a.y * w00 + b.y * w01 + g.y * w10 + h.y * w11;
    r.z = a.z * w00 + b.z * w01 + g.z * w10 + h.z * w11;
    r.w = a.w * w00 + b.w * w01 + g.w * w10 + h.w * w11;

    ((float4*)(out + (long)p * FEAT))[c] = r;
}

extern "C" void kernel_launch(void* const* d_in, const int* in_sizes, int n_in,
                              void* d_out, int out_size, void* d_ws, size_t ws_size,
                              hipStream_t stream)
{
    const float* inputs = (const float*)d_in[0];   // (batch, 2) fp32
    const float* emb    = (const float*)d_in[1];   // (16384, 1024) fp32
    float*       out    = (float*)d_out;           // (batch, 1024) fp32

    const int N = in_sizes[0] / 2;                 // 65536
    const size_t need = (size_t)(NBINS + N) * sizeof(unsigned);

    if (ws_size >= need) {
        unsigned* hist  = (unsigned*)d_ws;         // [NBINS]
        unsigned* order = hist + NBINS;            // [N]

        (void)hipMemsetAsync(hist, 0, NBINS * sizeof(unsigned), stream);
        hist_kernel<<<(N + 255) / 256, 256, 0, stream>>>(inputs, hist, N);
        scan_kernel<<<1, 256, 0, stream>>>(hist);
        scatter_kernel<<<(N + 255) / 256, 256, 0, stream>>>(inputs, hist, order, N);

        const int chunk = NBINS / 8;               // 16384 % 8 == 0 always
        DenseMap_cell_kernel<<<NBINS, 256, 0, stream>>>(inputs, emb, hist, order, out, chunk);
    } else {
        DenseMap_fallback_kernel<<<N, 256, 0, stream>>>(inputs, emb, out);
    }
}